// Round 2
// 146.935 us; speedup vs baseline: 1.0040x; 1.0040x over previous
//
#include <hip/hip_runtime.h>

#define SEQ 4096
#define EMB 1024
#define HS 64

typedef __attribute__((ext_vector_type(8))) short bf16x8;
typedef __attribute__((ext_vector_type(4))) short bf16x4;
typedef __attribute__((ext_vector_type(4))) float f32x4;

__device__ __forceinline__ unsigned short f2b(float f) {
    union { float f; unsigned u; } v; v.f = f;
    unsigned r = v.u + 0x7fffu + ((v.u >> 16) & 1u);
    return (unsigned short)(r >> 16);
}
__device__ __forceinline__ float b2f(unsigned short h) {
    union { unsigned u; float f; } v; v.u = ((unsigned)h) << 16;
    return v.f;
}
// packed f32x2 -> bf16x2 (RNE, same rounding as f2b); no builtin on gfx950
__device__ __forceinline__ unsigned cvtpk(float a, float b) {
    unsigned r;
    asm("v_cvt_pk_bf16_f32 %0, %1, %2" : "=v"(r) : "v"(a), "v"(b));
    return r;
}
// async global->LDS DMA, 16B/lane; LDS dst = wave-uniform base + lane*16
template <typename T>
__device__ __forceinline__ void gll16(const T* g, void* l) {
    __builtin_amdgcn_global_load_lds(
        (const __attribute__((address_space(1))) unsigned int*)(g),
        (__attribute__((address_space(3))) unsigned int*)(l), 16, 0, 0);
}

// ---------- W transpose + cast: Wt[192][1024] bf16; rows 0-63=Q (pre-scaled), 64-127=K, 128-191=V
__global__ __launch_bounds__(256) void wt_kernel(const float* __restrict__ Wq,
                                                 const float* __restrict__ Wk,
                                                 const float* __restrict__ Wv,
                                                 unsigned short* __restrict__ Wt) {
    int id = blockIdx.x * 256 + threadIdx.x;
    int mat = id >> 16;
    int rem = id & 65535;
    int k = rem >> 6;
    int n = rem & 63;
    const float* W = (mat == 0) ? Wq : (mat == 1) ? Wk : Wv;
    float scale = (mat == 0) ? 0.125f * 1.44269504f : 1.0f;   // fold 1/sqrt(64)*log2(e) into Q
    Wt[(mat * HS + n) * EMB + k] = f2b(W[k * HS + n] * scale);
}

// ---------- fused QKV projection (R12/R16-proven best): 32 rows x 192 cols, dbuf DMA staging ----------
__global__ __launch_bounds__(256, 2) void proj_kernel(const float* __restrict__ x,
                                                      const unsigned short* __restrict__ Wt,
                                                      unsigned short* __restrict__ Qb,
                                                      unsigned short* __restrict__ Kb,
                                                      unsigned short* __restrict__ Vt) {
    __shared__ float xf[2][32 * 64];              // 2 x 8 KiB, chunk swizzle c^(row&15)
    __shared__ unsigned short wb[2][192 * 64];    // 2 x 24 KiB, chunk swizzle c^(row&7)
    const int tid = threadIdx.x;
    const int wave = tid >> 6, lane = tid & 63;
    const int col = lane & 15, quad = lane >> 4;
    const int m0 = blockIdx.x * 32;
    const int b = m0 >> 12, t0 = m0 & 4095;

    const int xr_in = lane >> 4;
    const int xc = lane & 15;
    const int wr_in = lane >> 3;
    const int wc = lane & 7;

    f32x4 acc[2][3];
    #pragma unroll
    for (int i = 0; i < 2; i++)
        #pragma unroll
        for (int j = 0; j < 3; j++) acc[i][j] = (f32x4){0.f, 0.f, 0.f, 0.f};

    auto stage = [&](int k0, int bufi) {
        #pragma unroll
        for (int t = 0; t < 2; t++) {
            int R = (wave + t * 4) * 4;
            int row = R + xr_in;
            gll16(x + (size_t)(m0 + row) * EMB + k0 + ((xc ^ (row & 15)) << 2),
                  &xf[bufi][R * 64]);
        }
        #pragma unroll
        for (int t = 0; t < 6; t++) {
            int R = (wave * 6 + t) * 8;
            int row = R + wr_in;
            gll16(Wt + (size_t)row * EMB + k0 + ((wc ^ (row & 7)) << 3),
                  &wb[bufi][R * 64]);
        }
    };

    stage(0, 0);
    int buf = 0;
    #pragma unroll 1
    for (int k0 = 0; k0 < EMB; k0 += 64) {
        __syncthreads();
        if (k0 + 64 < EMB) stage(k0 + 64, buf ^ 1);
        #pragma unroll
        for (int kc = 0; kc < 2; kc++) {
            const int q2 = quad + kc * 4;
            bf16x8 af[2], bfr[3];
            #pragma unroll
            for (int mt = 0; mt < 2; mt++) {
                int rr = mt * 16 + col;
                float4 lo = *(const float4*)&xf[buf][rr * 64 + (((2 * q2) ^ col) << 2)];
                float4 hi = *(const float4*)&xf[buf][rr * 64 + (((2 * q2 + 1) ^ col) << 2)];
                bf16x8 a;
                a[0] = (short)f2b(lo.x); a[1] = (short)f2b(lo.y);
                a[2] = (short)f2b(lo.z); a[3] = (short)f2b(lo.w);
                a[4] = (short)f2b(hi.x); a[5] = (short)f2b(hi.y);
                a[6] = (short)f2b(hi.z); a[7] = (short)f2b(hi.w);
                af[mt] = a;
            }
            #pragma unroll
            for (int nt = 0; nt < 3; nt++) {
                int rn = wave * 48 + nt * 16 + col;
                bfr[nt] = *(const bf16x8*)&wb[buf][rn * 64 + ((q2 ^ (col & 7)) << 3)];
            }
            #pragma unroll
            for (int mt = 0; mt < 2; mt++)
                #pragma unroll
                for (int nt = 0; nt < 3; nt++)
                    acc[mt][nt] = __builtin_amdgcn_mfma_f32_16x16x32_bf16(af[mt], bfr[nt], acc[mt][nt], 0, 0, 0);
        }
        buf ^= 1;
    }

    #pragma unroll
    for (int mt = 0; mt < 2; mt++)
        #pragma unroll
        for (int nt = 0; nt < 3; nt++) {
            const int g = wave * 3 + nt;
            const int mat = g >> 2;
            const int ncol = (g & 3) * 16 + col;
            #pragma unroll
            for (int r = 0; r < 4; r++) {
                unsigned short val = f2b(acc[mt][nt][r]);
                int row = mt * 16 + quad * 4 + r;
                if (mat == 0)      Qb[(size_t)(m0 + row) * HS + ncol] = val;
                else if (mat == 1) Kb[(size_t)(m0 + row) * HS + ncol] = val;
                else               Vt[((size_t)b * HS + ncol) * SEQ + t0 + row] = val;
            }
        }
}

// ---------- flash attention (causal): 8-wave blocks, BM=128, TRIPLE-buffered DMA K/V ----------
// R17: swapped QK^T (S^T = mfma(K,Q)) puts P q-major on lane&15 and kv-local per quad:
// P stays in registers (cvt_pk -> PV A-frag directly); kv-permutation absorbed into V's
// LDS read addressing (two b64 per fragment, bank-balanced: 4 addrs/bank = b64 minimum).
// P_lds deleted: LDS 66.5->48 KB, per-step LDS traffic/wave 20KB->16KB, -16 ds_write_b16,
// -2 ds_read_b128, -~56 VALU per step.
// raw s_barrier + manual s_waitcnt vmcnt(2): 2-step DMA lookahead stays in flight across barriers.
// tile T: 2T+2 kv-steps; pieces of <=10; np(T)=T/5+1; grid 476 <= 512 slots (2 blocks/CU)
__global__ __launch_bounds__(512, 4) void attn_kernel(const unsigned short* __restrict__ Qb,
                                                      const unsigned short* __restrict__ Kb,
                                                      const unsigned short* __restrict__ Vt,
                                                      unsigned short* __restrict__ Opart,
                                                      float* __restrict__ Lpart,
                                                      float* __restrict__ out) {
    __shared__ unsigned short Kl[3][64 * 64];   // chunk swizzle c^(row&7)
    __shared__ unsigned short Vl[3][64 * 64];   // chunk swizzle c^(h&7)
    const int tid = threadIdx.x;
    const int wave = tid >> 6, lane = tid & 63;
    const int col = lane & 15, quad = lane >> 4;
    const int bid = blockIdx.x;            // 0..475
    const int g = 118 - (bid >> 2);        // longest-first piece id
    const int b = bid & 3;
    int T = 0, accp = 0;
    for (;;) { int np = T / 5 + 1; if (accp + np > g) break; accp += np; T++; }
    const int piece = g - accp;
    const int np = T / 5 + 1;
    const int q0 = T << 7;
    const int s_beg = piece * 10;
    const int s_end = min(s_beg + 10, 2 * T + 2);

    const unsigned short* Kp = Kb + ((size_t)(b << 12)) * HS;
    const unsigned short* Vp = Vt + (size_t)b * HS * SEQ;

    bf16x8 qf[2];
    #pragma unroll
    for (int c = 0; c < 2; c++)
        qf[c] = *(const bf16x8*)(Qb + ((size_t)(b << 12) + q0 + wave * 16 + col) * HS + quad * 8 + c * 32);

    f32x4 o[4];
    float l = 0.f;
    #pragma unroll
    for (int ct = 0; ct < 4; ct++) o[ct] = (f32x4){0.f, 0.f, 0.f, 0.f};

    const int r_in = lane >> 3;
    const int ch = lane & 7;

    auto stage = [&](int s, int bufi) {       // 2 DMA instrs per wave
        const int kv0 = s << 6;
        int R = wave * 8;
        int row = R + r_in;
        gll16(Kp + (size_t)(kv0 + row) * HS + ((ch ^ (row & 7)) << 3), &Kl[bufi][R * 64]);
        gll16(Vp + (size_t)row * SEQ + kv0 + ((ch ^ (row & 7)) << 3), &Vl[bufi][R * 64]);
    };

    // prologue: 2-step lookahead (4 DMA instrs outstanding)
    stage(s_beg, 0);
    stage(min(s_beg + 1, s_end - 1), 1);
    int bufr = 0;                              // buffer of step s: (s - s_beg) % 3
    const int grb = (b << 12) + q0 + wave * 16;
    const int qg = q0 + wave * 16 + col;       // this lane's q-row (swapped layout: q = lane&15)

    #pragma unroll 1
    for (int s = s_beg; s < s_end; s++) {
        // wait own step-s DMA (oldest 2 of <=4 outstanding), then barrier; s+1's stay in flight
        asm volatile("s_waitcnt vmcnt(2)\n\ts_barrier" ::: "memory");
        // issue step s+2 (clamped duplicate near the end -> uniform vmcnt bookkeeping; unread buffer)
        stage(min(s + 2, s_end - 1), (bufr + 2) % 3);
        const int kv0 = s << 6;

        // S^T = K * Q^T : C col = q (lane&15), C row = kv (quad*4+r within ct*16 tile)
        f32x4 sacc[4];
        #pragma unroll
        for (int ct = 0; ct < 4; ct++) sacc[ct] = (f32x4){0.f, 0.f, 0.f, 0.f};
        #pragma unroll
        for (int ct = 0; ct < 4; ct++) {
            int n = ct * 16 + col;
            #pragma unroll
            for (int kc = 0; kc < 2; kc++) {
                bf16x8 kf = *(const bf16x8*)&Kl[bufr][n * 64 + (((kc * 4 + quad) ^ (col & 7)) << 3)];
                sacc[ct] = __builtin_amdgcn_mfma_f32_16x16x32_bf16(kf, qf[kc], sacc[ct], 0, 0, 0);
            }
        }

        // softmax numerator + causal mask; l is a per-lane scalar (one q-row per lane)
        float p[4][4];
        #pragma unroll
        for (int ct = 0; ct < 4; ct++) {
            int kvb = kv0 + ct * 16 + quad * 4;
            #pragma unroll
            for (int r = 0; r < 4; r++) {
                float e = __builtin_exp2f(sacc[ct][r]);
                e = (kvb + r > qg) ? 0.f : e;
                p[ct][r] = e;
                l += e;
            }
        }

        // pack P -> PV A-fragment in-register: slot (kc, quad, j) <-> kv = 32kc + 16(j>>2) + 4quad + (j&3)
        bf16x8 pf[2];
        #pragma unroll
        for (int kc = 0; kc < 2; kc++) {
            union { unsigned u[4]; bf16x8 v; } pu;
            pu.u[0] = cvtpk(p[2 * kc][0],     p[2 * kc][1]);
            pu.u[1] = cvtpk(p[2 * kc][2],     p[2 * kc][3]);
            pu.u[2] = cvtpk(p[2 * kc + 1][0], p[2 * kc + 1][1]);
            pu.u[3] = cvtpk(p[2 * kc + 1][2], p[2 * kc + 1][3]);
            pf[kc] = pu.v;
        }

        // PV: B-frag k-slot reads V rows in the SAME permuted kv order (two b64 runs, 16 apart)
        #pragma unroll
        for (int ct = 0; ct < 4; ct++) {
            const unsigned short* Vrow = &Vl[bufr][(ct * 16 + col) * 64];
            #pragma unroll
            for (int kc = 0; kc < 2; kc++) {
                int c0 = ((kc << 2) + (quad >> 1)) ^ (col & 7);
                int c1 = ((kc << 2) + 2 + (quad >> 1)) ^ (col & 7);
                bf16x4 lo = *(const bf16x4*)&Vrow[(c0 << 3) + ((quad & 1) << 2)];
                bf16x4 hi = *(const bf16x4*)&Vrow[(c1 << 3) + ((quad & 1) << 2)];
                bf16x8 vf = __builtin_shufflevector(lo, hi, 0, 1, 2, 3, 4, 5, 6, 7);
                o[ct] = __builtin_amdgcn_mfma_f32_16x16x32_bf16(pf[kc], vf, o[ct], 0, 0, 0);
            }
        }
        bufr = (bufr == 2) ? 0 : bufr + 1;
    }

    // row-sum lives on q = lane&15; reduce across quads only
    l += __shfl_xor(l, 16, 64);
    l += __shfl_xor(l, 32, 64);

    if (np == 1) {
        // single-piece tile (T<=4): write output directly, no partials
        float lq[4];
        #pragma unroll
        for (int r = 0; r < 4; r++) lq[r] = __shfl(l, quad * 4 + r, 64);
        #pragma unroll
        for (int ct = 0; ct < 4; ct++)
            #pragma unroll
            for (int r = 0; r < 4; r++)
                out[(size_t)(grb + quad * 4 + r) * HS + ct * 16 + col] = o[ct][r] / lq[r];
    } else {
        // bf16 partials (plain stores, proven fast); O layout unchanged (col=h, row=q)
        const int widx = bid * 8 + wave;
        unsigned short* Op = Opart + (size_t)widx * 1024;
        #pragma unroll
        for (int ct = 0; ct < 4; ct++) {
            ushort4 st;
            st.x = f2b(o[ct][0]); st.y = f2b(o[ct][1]);
            st.z = f2b(o[ct][2]); st.w = f2b(o[ct][3]);
            *(ushort4*)(Op + ct * 256 + lane * 4) = st;
        }
        if (quad == 0) Lpart[widx * 16 + col] = l;
    }
}

// ---------- combine split-KV partials for T>=5 (np>=2): coalesced ushort4 reads ----------
__global__ __launch_bounds__(256) void comb_kernel(const unsigned short* __restrict__ Opart,
                                                   const float* __restrict__ Lpart,
                                                   float* __restrict__ out) {
    const int bid = blockIdx.x;            // 864 = 4 b x 27 T x 8 wave
    const int b = bid & 3;
    const int idx = bid >> 2;              // 0..215
    const int T = 5 + (idx % 27);
    const int wave = idx / 27;             // 0..7
    const int tid = threadIdx.x;
    const int lane = tid & 63, ct = tid >> 6;
    const int col = lane & 15, quad = lane >> 4;

    const int q = T / 5, r5 = T % 5;
    const int base = T + 5 * q * (q - 1) / 2 + r5 * q;   // piece-id prefix for S=10
    const int np = q + 1;

    float acc[4] = {0.f, 0.f, 0.f, 0.f};
    float l[4] = {0.f, 0.f, 0.f, 0.f};
    for (int p = 0; p < np; p++) {
        int gg = base + p;
        int bidp = ((118 - gg) << 2) | b;
        int widx = bidp * 8 + wave;
        ushort4 v = *(const ushort4*)(Opart + (size_t)widx * 1024 + ct * 256 + lane * 4);
        acc[0] += b2f(v.x); acc[1] += b2f(v.y);
        acc[2] += b2f(v.z); acc[3] += b2f(v.w);
        #pragma unroll
        for (int r = 0; r < 4; r++)
            l[r] += Lpart[widx * 16 + quad * 4 + r];
    }
    const size_t rowb = (size_t)(b << 12) + (T << 7) + wave * 16 + quad * 4;
    #pragma unroll
    for (int r = 0; r < 4; r++)
        out[(rowb + r) * HS + ct * 16 + col] = acc[r] / l[r];
}

extern "C" void kernel_launch(void* const* d_in, const int* in_sizes, int n_in,
                              void* d_out, int out_size, void* d_ws, size_t ws_size,
                              hipStream_t stream) {
    const float* x  = (const float*)d_in[0];
    const float* Wk = (const float*)d_in[1];
    const float* Wq = (const float*)d_in[2];
    const float* Wv = (const float*)d_in[3];
    float* out = (float*)d_out;

    char* ws = (char*)d_ws;
    unsigned short* Wt = (unsigned short*)(ws);                 // 393216 B
    unsigned short* Qb = (unsigned short*)(ws + 393216);        // 2 MiB
    unsigned short* Kb = (unsigned short*)(ws + 2490368);       // 2 MiB
    unsigned short* Vt = (unsigned short*)(ws + 4587520);       // 2 MiB
    unsigned short* Opart = (unsigned short*)(ws + 6684672);    // 476*8*1024*2 = 7.80 MB
    float* Lpart          = (float*)(ws + 14483456);            // 476*8*16*4 = 243712 B

    wt_kernel<<<dim3(768), dim3(256), 0, stream>>>(Wq, Wk, Wv, Wt);
    proj_kernel<<<dim3(512), dim3(256), 0, stream>>>(x, Wt, Qb, Kb, Vt);
    attn_kernel<<<dim3(476), dim3(512), 0, stream>>>(Qb, Kb, Vt, Opart, Lpart, out);
    comb_kernel<<<dim3(864), dim3(256), 0, stream>>>(Opart, Lpart, out);
}

// Round 5
// 146.095 us; speedup vs baseline: 1.0098x; 1.0058x over previous
//
#include <hip/hip_runtime.h>

#define SEQ 4096
#define EMB 1024
#define HS 64

typedef __attribute__((ext_vector_type(8))) short bf16x8;
typedef __attribute__((ext_vector_type(4))) short bf16x4;
typedef __attribute__((ext_vector_type(4))) float f32x4;

__device__ __forceinline__ unsigned short f2b(float f) {
    union { float f; unsigned u; } v; v.f = f;
    unsigned r = v.u + 0x7fffu + ((v.u >> 16) & 1u);
    return (unsigned short)(r >> 16);
}
__device__ __forceinline__ float b2f(unsigned short h) {
    union { unsigned u; float f; } v; v.u = ((unsigned)h) << 16;
    return v.f;
}
// packed f32x2 -> bf16x2 (RNE, same rounding as f2b); no builtin on gfx950
__device__ __forceinline__ unsigned cvtpk(float a, float b) {
    unsigned r;
    asm("v_cvt_pk_bf16_f32 %0, %1, %2" : "=v"(r) : "v"(a), "v"(b));
    return r;
}
// async global->LDS DMA, 16B/lane; LDS dst = wave-uniform base + lane*16
template <typename T>
__device__ __forceinline__ void gll16(const T* g, void* l) {
    __builtin_amdgcn_global_load_lds(
        (const __attribute__((address_space(1))) unsigned int*)(g),
        (__attribute__((address_space(3))) unsigned int*)(l), 16, 0, 0);
}

// ---------- W transpose + cast: Wt[192][1024] bf16; rows 0-63=Q (pre-scaled), 64-127=K, 128-191=V
__global__ __launch_bounds__(256) void wt_kernel(const float* __restrict__ Wq,
                                                 const float* __restrict__ Wk,
                                                 const float* __restrict__ Wv,
                                                 unsigned short* __restrict__ Wt) {
    int id = blockIdx.x * 256 + threadIdx.x;
    int mat = id >> 16;
    int rem = id & 65535;
    int k = rem >> 6;
    int n = rem & 63;
    const float* W = (mat == 0) ? Wq : (mat == 1) ? Wk : Wv;
    float scale = (mat == 0) ? 0.125f * 1.44269504f : 1.0f;   // fold 1/sqrt(64)*log2(e) into Q
    Wt[(mat * HS + n) * EMB + k] = f2b(W[k * HS + n] * scale);
}

// ---------- fused QKV projection (R12/R16-proven best): 32 rows x 192 cols, dbuf DMA staging ----------
__global__ __launch_bounds__(256, 2) void proj_kernel(const float* __restrict__ x,
                                                      const unsigned short* __restrict__ Wt,
                                                      unsigned short* __restrict__ Qb,
                                                      unsigned short* __restrict__ Kb,
                                                      unsigned short* __restrict__ Vt) {
    __shared__ float xf[2][32 * 64];              // 2 x 8 KiB, chunk swizzle c^(row&15)
    __shared__ unsigned short wb[2][192 * 64];    // 2 x 24 KiB, chunk swizzle c^(row&7)
    const int tid = threadIdx.x;
    const int wave = tid >> 6, lane = tid & 63;
    const int col = lane & 15, quad = lane >> 4;
    const int m0 = blockIdx.x * 32;
    const int b = m0 >> 12, t0 = m0 & 4095;

    const int xr_in = lane >> 4;
    const int xc = lane & 15;
    const int wr_in = lane >> 3;
    const int wc = lane & 7;

    f32x4 acc[2][3];
    #pragma unroll
    for (int i = 0; i < 2; i++)
        #pragma unroll
        for (int j = 0; j < 3; j++) acc[i][j] = (f32x4){0.f, 0.f, 0.f, 0.f};

    auto stage = [&](int k0, int bufi) {
        #pragma unroll
        for (int t = 0; t < 2; t++) {
            int R = (wave + t * 4) * 4;
            int row = R + xr_in;
            gll16(x + (size_t)(m0 + row) * EMB + k0 + ((xc ^ (row & 15)) << 2),
                  &xf[bufi][R * 64]);
        }
        #pragma unroll
        for (int t = 0; t < 6; t++) {
            int R = (wave * 6 + t) * 8;
            int row = R + wr_in;
            gll16(Wt + (size_t)row * EMB + k0 + ((wc ^ (row & 7)) << 3),
                  &wb[bufi][R * 64]);
        }
    };

    stage(0, 0);
    int buf = 0;
    #pragma unroll 1
    for (int k0 = 0; k0 < EMB; k0 += 64) {
        __syncthreads();
        if (k0 + 64 < EMB) stage(k0 + 64, buf ^ 1);
        #pragma unroll
        for (int kc = 0; kc < 2; kc++) {
            const int q2 = quad + kc * 4;
            bf16x8 af[2], bfr[3];
            #pragma unroll
            for (int mt = 0; mt < 2; mt++) {
                int rr = mt * 16 + col;
                float4 lo = *(const float4*)&xf[buf][rr * 64 + (((2 * q2) ^ col) << 2)];
                float4 hi = *(const float4*)&xf[buf][rr * 64 + (((2 * q2 + 1) ^ col) << 2)];
                bf16x8 a;
                a[0] = (short)f2b(lo.x); a[1] = (short)f2b(lo.y);
                a[2] = (short)f2b(lo.z); a[3] = (short)f2b(lo.w);
                a[4] = (short)f2b(hi.x); a[5] = (short)f2b(hi.y);
                a[6] = (short)f2b(hi.z); a[7] = (short)f2b(hi.w);
                af[mt] = a;
            }
            #pragma unroll
            for (int nt = 0; nt < 3; nt++) {
                int rn = wave * 48 + nt * 16 + col;
                bfr[nt] = *(const bf16x8*)&wb[buf][rn * 64 + ((q2 ^ (col & 7)) << 3)];
            }
            #pragma unroll
            for (int mt = 0; mt < 2; mt++)
                #pragma unroll
                for (int nt = 0; nt < 3; nt++)
                    acc[mt][nt] = __builtin_amdgcn_mfma_f32_16x16x32_bf16(af[mt], bfr[nt], acc[mt][nt], 0, 0, 0);
        }
        buf ^= 1;
    }

    #pragma unroll
    for (int mt = 0; mt < 2; mt++)
        #pragma unroll
        for (int nt = 0; nt < 3; nt++) {
            const int g = wave * 3 + nt;
            const int mat = g >> 2;
            const int ncol = (g & 3) * 16 + col;
            #pragma unroll
            for (int r = 0; r < 4; r++) {
                unsigned short val = f2b(acc[mt][nt][r]);
                int row = mt * 16 + quad * 4 + r;
                if (mat == 0)      Qb[(size_t)(m0 + row) * HS + ncol] = val;
                else if (mat == 1) Kb[(size_t)(m0 + row) * HS + ncol] = val;
                else               Vt[((size_t)b * HS + ncol) * SEQ + t0 + row] = val;
            }
        }
}

// ---------- flash attention (causal): 4-wave blocks, BM=128 (32 q-rows/wave), TRIPLE-buffered DMA K/V ----------
// R18: halve LDS-read redundancy. Every wave must consume the full 8KB K + 8KB V tile per step;
// read volume scales with #waves. 4 waves x 32 q-rows: each kf/vf fragment feeds TWO mfma
// (mq=0,1), so per-block-step LDS traffic drops 144KB -> 80KB (-44%). Fragment math identical
// to R17 (swapped QK^T, pi-permuted V b64 reads, cvt_pk P-pack). widx = bid*8 + wave*2 + mq
// preserves Opart/Lpart layout; comb unchanged.
// raw s_barrier + s_waitcnt vmcnt(4): 4 DMA/stage, 2-step lookahead stays in flight across barriers.
// tile T: 2T+2 kv-steps; pieces of <=10; np(T)=T/5+1; grid 476; 3 blocks/CU (LDS 48KB), VGPR cap 170
__global__ __launch_bounds__(256, 3) void attn_kernel(const unsigned short* __restrict__ Qb,
                                                      const unsigned short* __restrict__ Kb,
                                                      const unsigned short* __restrict__ Vt,
                                                      unsigned short* __restrict__ Opart,
                                                      float* __restrict__ Lpart,
                                                      float* __restrict__ out) {
    __shared__ unsigned short Kl[3][64 * 64];   // chunk swizzle c^(row&7)
    __shared__ unsigned short Vl[3][64 * 64];   // chunk swizzle c^(h&7)
    const int tid = threadIdx.x;
    const int wave = tid >> 6, lane = tid & 63;  // wave 0..3
    const int col = lane & 15, quad = lane >> 4;
    const int bid = blockIdx.x;            // 0..475
    const int g = 118 - (bid >> 2);        // longest-first piece id
    const int b = bid & 3;
    int T = 0, accp = 0;
    for (;;) { int np = T / 5 + 1; if (accp + np > g) break; accp += np; T++; }
    const int piece = g - accp;
    const int np = T / 5 + 1;
    const int q0 = T << 7;
    const int s_beg = piece * 10;
    const int s_end = min(s_beg + 10, 2 * T + 2);

    const unsigned short* Kp = Kb + ((size_t)(b << 12)) * HS;
    const unsigned short* Vp = Vt + (size_t)b * HS * SEQ;

    bf16x8 qf[2][2];
    #pragma unroll
    for (int mq = 0; mq < 2; mq++)
        #pragma unroll
        for (int c = 0; c < 2; c++)
            qf[mq][c] = *(const bf16x8*)(Qb + ((size_t)(b << 12) + q0 + wave * 32 + mq * 16 + col) * HS + quad * 8 + c * 32);

    f32x4 o[2][4];
    float l[2] = {0.f, 0.f};
    #pragma unroll
    for (int mq = 0; mq < 2; mq++)
        #pragma unroll
        for (int ct = 0; ct < 4; ct++) o[mq][ct] = (f32x4){0.f, 0.f, 0.f, 0.f};

    const int r_in = lane >> 3;
    const int ch = lane & 7;

    auto stage = [&](int s, int bufi) {       // 4 DMA instrs per wave (K x2, V x2)
        const int kv0 = s << 6;
        #pragma unroll
        for (int t = 0; t < 2; t++) {
            int R = wave * 16 + t * 8;
            int row = R + r_in;
            gll16(Kp + (size_t)(kv0 + row) * HS + ((ch ^ (row & 7)) << 3), &Kl[bufi][R * 64]);
            gll16(Vp + (size_t)row * SEQ + kv0 + ((ch ^ (row & 7)) << 3), &Vl[bufi][R * 64]);
        }
    };

    // prologue: 2-step lookahead (8 DMA instrs outstanding)
    stage(s_beg, 0);
    stage(min(s_beg + 1, s_end - 1), 1);
    int bufr = 0;                              // buffer of step s: (s - s_beg) % 3
    const int grb = (b << 12) + q0 + wave * 32;
    const int qgb = q0 + wave * 32 + col;      // q-row of lane (mq=0); +16 for mq=1

    #pragma unroll 1
    for (int s = s_beg; s < s_end; s++) {
        // wait own step-s DMA (oldest 4 of <=8 outstanding), then barrier; s+1's stay in flight
        asm volatile("s_waitcnt vmcnt(4)\n\ts_barrier" ::: "memory");
        // issue step s+2 (clamped duplicate near the end -> uniform vmcnt bookkeeping; unread buffer)
        stage(min(s + 2, s_end - 1), (bufr + 2) % 3);
        const int kv0 = s << 6;

        // S^T = K * Q^T : C col = q (lane&15), C row = kv (quad*4+r); each kf feeds both mq
        f32x4 sacc[2][4];
        #pragma unroll
        for (int mq = 0; mq < 2; mq++)
            #pragma unroll
            for (int ct = 0; ct < 4; ct++) sacc[mq][ct] = (f32x4){0.f, 0.f, 0.f, 0.f};
        #pragma unroll
        for (int ct = 0; ct < 4; ct++) {
            int n = ct * 16 + col;
            #pragma unroll
            for (int kc = 0; kc < 2; kc++) {
                bf16x8 kf = *(const bf16x8*)&Kl[bufr][n * 64 + (((kc * 4 + quad) ^ (col & 7)) << 3)];
                sacc[0][ct] = __builtin_amdgcn_mfma_f32_16x16x32_bf16(kf, qf[0][kc], sacc[0][ct], 0, 0, 0);
                sacc[1][ct] = __builtin_amdgcn_mfma_f32_16x16x32_bf16(kf, qf[1][kc], sacc[1][ct], 0, 0, 0);
            }
        }

        // softmax numerator + causal mask + P->A-frag pack, per mq
        bf16x8 pf[2][2];
        #pragma unroll
        for (int mq = 0; mq < 2; mq++) {
            const int qg = qgb + mq * 16;
            float p[4][4];
            #pragma unroll
            for (int ct = 0; ct < 4; ct++) {
                int kvb = kv0 + ct * 16 + quad * 4;
                #pragma unroll
                for (int r = 0; r < 4; r++) {
                    float e = __builtin_exp2f(sacc[mq][ct][r]);
                    e = (kvb + r > qg) ? 0.f : e;
                    p[ct][r] = e;
                    l[mq] += e;
                }
            }
            // slot (kc, quad, j) <-> kv = 32kc + 16(j>>2) + 4quad + (j&3)
            #pragma unroll
            for (int kc = 0; kc < 2; kc++) {
                union { unsigned u[4]; bf16x8 v; } pu;
                pu.u[0] = cvtpk(p[2 * kc][0],     p[2 * kc][1]);
                pu.u[1] = cvtpk(p[2 * kc][2],     p[2 * kc][3]);
                pu.u[2] = cvtpk(p[2 * kc + 1][0], p[2 * kc + 1][1]);
                pu.u[3] = cvtpk(p[2 * kc + 1][2], p[2 * kc + 1][3]);
                pf[mq][kc] = pu.v;
            }
        }

        // PV: B-frag reads V rows in the SAME permuted kv order (two b64 runs, 16 apart); each vf feeds both mq
        #pragma unroll
        for (int ct = 0; ct < 4; ct++) {
            const unsigned short* Vrow = &Vl[bufr][(ct * 16 + col) * 64];
            #pragma unroll
            for (int kc = 0; kc < 2; kc++) {
                int c0 = ((kc << 2) + (quad >> 1)) ^ (col & 7);
                int c1 = ((kc << 2) + 2 + (quad >> 1)) ^ (col & 7);
                bf16x4 lo = *(const bf16x4*)&Vrow[(c0 << 3) + ((quad & 1) << 2)];
                bf16x4 hi = *(const bf16x4*)&Vrow[(c1 << 3) + ((quad & 1) << 2)];
                bf16x8 vf = __builtin_shufflevector(lo, hi, 0, 1, 2, 3, 4, 5, 6, 7);
                o[0][ct] = __builtin_amdgcn_mfma_f32_16x16x32_bf16(pf[0][kc], vf, o[0][ct], 0, 0, 0);
                o[1][ct] = __builtin_amdgcn_mfma_f32_16x16x32_bf16(pf[1][kc], vf, o[1][ct], 0, 0, 0);
            }
        }
        bufr = (bufr == 2) ? 0 : bufr + 1;
    }

    // row-sum lives on q = lane&15; reduce across quads only
    #pragma unroll
    for (int mq = 0; mq < 2; mq++) {
        l[mq] += __shfl_xor(l[mq], 16, 64);
        l[mq] += __shfl_xor(l[mq], 32, 64);
    }

    if (np == 1) {
        // single-piece tile (T<=4): write output directly, no partials
        #pragma unroll
        for (int mq = 0; mq < 2; mq++) {
            float lq[4];
            #pragma unroll
            for (int r = 0; r < 4; r++) lq[r] = __shfl(l[mq], quad * 4 + r, 64);
            #pragma unroll
            for (int ct = 0; ct < 4; ct++)
                #pragma unroll
                for (int r = 0; r < 4; r++)
                    out[(size_t)(grb + mq * 16 + quad * 4 + r) * HS + ct * 16 + col] = o[mq][ct][r] / lq[r];
        }
    } else {
        // bf16 partials (plain stores, proven fast); widx low bits = q-chunk index, same as 8-wave layout
        #pragma unroll
        for (int mq = 0; mq < 2; mq++) {
            const int widx = bid * 8 + wave * 2 + mq;
            unsigned short* Op = Opart + (size_t)widx * 1024;
            #pragma unroll
            for (int ct = 0; ct < 4; ct++) {
                ushort4 st;
                st.x = f2b(o[mq][ct][0]); st.y = f2b(o[mq][ct][1]);
                st.z = f2b(o[mq][ct][2]); st.w = f2b(o[mq][ct][3]);
                *(ushort4*)(Op + ct * 256 + lane * 4) = st;
            }
            if (quad == 0) Lpart[widx * 16 + col] = l[mq];
        }
    }
}

// ---------- combine split-KV partials for T>=5 (np>=2): coalesced ushort4 reads ----------
__global__ __launch_bounds__(256) void comb_kernel(const unsigned short* __restrict__ Opart,
                                                   const float* __restrict__ Lpart,
                                                   float* __restrict__ out) {
    const int bid = blockIdx.x;            // 864 = 4 b x 27 T x 8 wave
    const int b = bid & 3;
    const int idx = bid >> 2;              // 0..215
    const int T = 5 + (idx % 27);
    const int wave = idx / 27;             // 0..7
    const int tid = threadIdx.x;
    const int lane = tid & 63, ct = tid >> 6;
    const int col = lane & 15, quad = lane >> 4;

    const int q = T / 5, r5 = T % 5;
    const int base = T + 5 * q * (q - 1) / 2 + r5 * q;   // piece-id prefix for S=10
    const int np = q + 1;

    float acc[4] = {0.f, 0.f, 0.f, 0.f};
    float l[4] = {0.f, 0.f, 0.f, 0.f};
    for (int p = 0; p < np; p++) {
        int gg = base + p;
        int bidp = ((118 - gg) << 2) | b;
        int widx = bidp * 8 + wave;
        ushort4 v = *(const ushort4*)(Opart + (size_t)widx * 1024 + ct * 256 + lane * 4);
        acc[0] += b2f(v.x); acc[1] += b2f(v.y);
        acc[2] += b2f(v.z); acc[3] += b2f(v.w);
        #pragma unroll
        for (int r = 0; r < 4; r++)
            l[r] += Lpart[widx * 16 + quad * 4 + r];
    }
    const size_t rowb = (size_t)(b << 12) + (T << 7) + wave * 16 + quad * 4;
    #pragma unroll
    for (int r = 0; r < 4; r++)
        out[(rowb + r) * HS + ct * 16 + col] = acc[r] / l[r];
}

extern "C" void kernel_launch(void* const* d_in, const int* in_sizes, int n_in,
                              void* d_out, int out_size, void* d_ws, size_t ws_size,
                              hipStream_t stream) {
    const float* x  = (const float*)d_in[0];
    const float* Wk = (const float*)d_in[1];
    const float* Wq = (const float*)d_in[2];
    const float* Wv = (const float*)d_in[3];
    float* out = (float*)d_out;

    char* ws = (char*)d_ws;
    unsigned short* Wt = (unsigned short*)(ws);                 // 393216 B
    unsigned short* Qb = (unsigned short*)(ws + 393216);        // 2 MiB
    unsigned short* Kb = (unsigned short*)(ws + 2490368);       // 2 MiB
    unsigned short* Vt = (unsigned short*)(ws + 4587520);       // 2 MiB
    unsigned short* Opart = (unsigned short*)(ws + 6684672);    // 476*8*1024*2 = 7.80 MB
    float* Lpart          = (float*)(ws + 14483456);            // 476*8*16*4 = 243712 B

    wt_kernel<<<dim3(768), dim3(256), 0, stream>>>(Wq, Wk, Wv, Wt);
    proj_kernel<<<dim3(512), dim3(256), 0, stream>>>(x, Wt, Qb, Kb, Vt);
    attn_kernel<<<dim3(476), dim3(256), 0, stream>>>(Qb, Kb, Vt, Opart, Lpart, out);
    comb_kernel<<<dim3(864), dim3(256), 0, stream>>>(Opart, Lpart, out);
}